// Round 3
// baseline (87.046 us; speedup 1.0000x reference)
//
#include <hip/hip_runtime.h>

// MultiLinear: out[n,h] = sum_d x[n,d] * W[idx[n],d,h] + b[idx[n],h]
// N=2048, D=512, H=512, NH=16. fp32 in/out, bf16 MFMA internally.
//
// R9 (resubmit; R2 bench was an infra failure, container never acquired).
// XCD-colocated heads. R8 (-1.3us vs predicted -6..9) showed the ~20us
// controllable slice is insensitive to occupancy/launch count. Theory:
// m-loop x re-reads (16 stripe-blocks x 4MB, spread over 8 non-coherent L2s,
// L3 thrashed by the 256MiB poison fill) cost up to ~30MB of degraded-BW HBM
// traffic. Fixes:
// (a) bid remap head=2*(bid&7)+((bid>>3)&1), stripe=bid>>4 -- all 16 stripe
//     blocks of a head land on ONE XCD (hw round-robin bid%8->XCD), so each
//     x row is HBM-fetched once and L2-served 15 times (~512KB/XCD in 4MiB);
// (b) Bl convert writes as b128 row-writes (was 8-way-conflicted b32s);
// (c) everything else identical to R8.

#define N_SAMPLES 2048
#define DIM       512
#define HDIM      512
#define N_HEADS   16
#define SH        32              // h-columns per block = 2 MFMA n-tiles
#define BPITCH    520             // ushorts per Bl row: 1040B, 16B-aligned rows

typedef __attribute__((ext_vector_type(8))) short bf16x8;
typedef __attribute__((ext_vector_type(4))) float floatx4;

__device__ inline unsigned short f2bf_rne(float f) {
    union { float f; unsigned u; } v; v.f = f;
    return (unsigned short)((v.u + 0x7FFFu + ((v.u >> 16) & 1u)) >> 16);
}
__device__ inline unsigned bfpack_rne(float lo, float hi) {   // bf16(lo)|bf16(hi)<<16
    return (unsigned)f2bf_rne(lo) | ((unsigned)f2bf_rne(hi) << 16);
}

__global__ __launch_bounds__(512, 2) void fused(
    const float* __restrict__ x,             // N x D fp32
    const int*   __restrict__ idx,           // N
    const float* __restrict__ w,             // NH x D x H fp32
    const float* __restrict__ bias,          // NH x H fp32
    float*       __restrict__ out)           // N x H fp32
{
    __shared__ unsigned short Bl[SH * BPITCH];      // 33.3 KB, [h][d] bf16
    __shared__ unsigned short slist[N_SAMPLES];     // 4 KB
    __shared__ int wcnt[8];

    const int bid  = blockIdx.x;                    // 256 blocks
    // XCD colocation: hw assigns XCD = bid % 8. Give each XCD 2 whole heads
    // so all 16 stripe-blocks of a head share one L2 (x-row reuse).
    const int head = 2 * (bid & 7) + ((bid >> 3) & 1);
    const int h0   = (bid >> 4) * SH;
    const int t    = threadIdx.x;
    const int wave = t >> 6;                        // 0..7
    const int lane = t & 63;
    const int l16  = lane & 15;
    const int quad = lane >> 4;

    // ---- idx loads first (oldest in flight; ballot waits only on these) ----
    int myidx[4];
    #pragma unroll
    for (int c = 0; c < 4; ++c)
        myidx[c] = idx[(wave * 4 + c) * 64 + lane];

    // ---- issue ALL W loads into regs (row-contiguous: lanes 0..7 cover one
    //      128B d-row segment; 8 float4/thread = whole 512d x 32h stripe) ----
    const int hh = (t & 7) * 4;                     // 0..28
    const int dg = t >> 3;                          // 0..63, d-range [dg*8, +8)
    const float* wg = w + (size_t)head * DIM * HDIM + h0;
    float4 q[8];
    #pragma unroll
    for (int s = 0; s < 8; ++s)
        q[s] = *(const float4*)(wg + (size_t)(dg * 8 + s) * HDIM + hh);

    // ---- ballot compaction (overlaps W-load flight; waits only idx) ----
    unsigned long long masks[4];
    {
        int mycnt = 0;
        #pragma unroll
        for (int c = 0; c < 4; ++c) {
            masks[c] = __ballot(myidx[c] == head);
            mycnt += __popcll(masks[c]);
        }
        if (lane == 0) wcnt[wave] = mycnt;
    }
    __syncthreads();                                // wcnt visible
    int cnt = 0, base = 0;
    #pragma unroll
    for (int i = 0; i < 8; ++i) { if (i < wave) base += wcnt[i]; cnt += wcnt[i]; }
    {
        int pos = base;
        #pragma unroll
        for (int c = 0; c < 4; ++c) {
            const unsigned long long m = masks[c];
            if (m & (1ull << lane)) {
                const int rank = __popcll(m & ((1ull << lane) - 1ull));
                slist[pos + rank] = (unsigned short)((wave * 4 + c) * 64 + lane);
            }
            pos += __popcll(m);
        }
    }

    // ---- convert staged W and write Bl[h][d]: one b128 per h-row (16B of
    //      consecutive d), conflict-free (was 8-way-conflicted b32s) ----
    #pragma unroll
    for (int k = 0; k < 4; ++k) {
        uint4 o;
        o.x = bfpack_rne(((const float*)&q[0])[k], ((const float*)&q[1])[k]);
        o.y = bfpack_rne(((const float*)&q[2])[k], ((const float*)&q[3])[k]);
        o.z = bfpack_rne(((const float*)&q[4])[k], ((const float*)&q[5])[k]);
        o.w = bfpack_rne(((const float*)&q[6])[k], ((const float*)&q[7])[k]);
        *(uint4*)&Bl[(hh + k) * BPITCH + dg * 8] = o;
    }
    __syncthreads();                                // Bl + slist visible

    const int   mt  = (cnt + 15) >> 4;              // m-tiles for this head
    const float bv0 = bias[head * HDIM + h0 + l16];
    const float bv1 = bias[head * HDIM + h0 + 16 + l16];

    // ---- m-loop: wave owns m-tiles j = wave, wave+8, ... (mostly 1/wave) ----
    for (int j = wave; j < mt; j += 8) {
        const int mg  = j * 16 + l16;
        const int row = slist[mg < cnt ? mg : cnt - 1];
        const float* ap = x + (size_t)row * DIM + quad * 8;

        floatx4 acc0 = {0.f, 0.f, 0.f, 0.f};
        floatx4 acc1 = {0.f, 0.f, 0.f, 0.f};
        #pragma unroll
        for (int ks = 0; ks < 16; ++ks) {
            const float4 v0 = *(const float4*)(ap + ks * 32);
            const float4 v1 = *(const float4*)(ap + ks * 32 + 4);
            union { bf16x8 v; unsigned u[4]; } A;
            A.u[0] = bfpack_rne(v0.x, v0.y);
            A.u[1] = bfpack_rne(v0.z, v0.w);
            A.u[2] = bfpack_rne(v1.x, v1.y);
            A.u[3] = bfpack_rne(v1.z, v1.w);
            const bf16x8 b0 = *(const bf16x8*)&Bl[l16 * BPITCH + ks * 32 + quad * 8];
            const bf16x8 b1 = *(const bf16x8*)&Bl[(16 + l16) * BPITCH + ks * 32 + quad * 8];
            acc0 = __builtin_amdgcn_mfma_f32_16x16x32_bf16(A.v, b0, acc0, 0, 0, 0);
            acc1 = __builtin_amdgcn_mfma_f32_16x16x32_bf16(A.v, b1, acc1, 0, 0, 0);
        }

        // C[m][n]: n = l16 (h), sample row = quad*4 + r; 64B-contiguous stores
        #pragma unroll
        for (int r = 0; r < 4; ++r) {
            const int mm = j * 16 + quad * 4 + r;
            if (mm < cnt) {
                const int rg = slist[mm];
                out[(size_t)rg * HDIM + h0 + l16]      = acc0[r] + bv0;
                out[(size_t)rg * HDIM + h0 + 16 + l16] = acc1[r] + bv1;
            }
        }
    }
}

extern "C" void kernel_launch(void* const* d_in, const int* in_sizes, int n_in,
                              void* d_out, int out_size, void* d_ws, size_t ws_size,
                              hipStream_t stream) {
    const float* x   = (const float*)d_in[0];
    const int*   idx = (const int*)  d_in[1];
    const float* w   = (const float*)d_in[2];
    const float* b   = (const float*)d_in[3];
    float*       out = (float*)d_out;
    (void)d_ws; (void)ws_size;

    fused<<<N_HEADS * (HDIM / SH), 512, 0, stream>>>(x, idx, w, b, out);
}

// Round 5
// 85.254 us; speedup vs baseline: 1.0210x; 1.0210x over previous
//
#include <hip/hip_runtime.h>

// MultiLinear: out[n,h] = sum_d x[n,d] * W[idx[n],d,h] + b[idx[n],h]
// N=2048, D=512, H=512, NH=16. fp32 in/out, bf16 MFMA internally.
//
// R11 = R10 with compile fix: __builtin_nontemporal_load requires an
// ext_vector pointer, not HIP_vector_type<float,4> -- W/x tiles now use the
// clang ext-vector floatx4. Logic unchanged from R10:
// (a) extra barrier after compaction; each wave issues its full A-tile
//     (32 x 16B -> regs) BEFORE the W drain, overlapping x cold-miss service
//     with the W stream (T14 issue-early, adapted);
// (b) W loads and out stores nontemporal (read/written exactly once
//     machine-wide) -- no L2/L3 allocation, no dirty-poison writeback evictions;
// (c) R8 bid mapping (best measured); Bl b128 row-writes kept.

#define N_SAMPLES 2048
#define DIM       512
#define HDIM      512
#define N_HEADS   16
#define SH        32              // h-columns per block = 2 MFMA n-tiles
#define BPITCH    520             // ushorts per Bl row: 1040B, 16B-aligned rows

typedef __attribute__((ext_vector_type(8))) short bf16x8;
typedef __attribute__((ext_vector_type(4))) float floatx4;

__device__ inline unsigned short f2bf_rne(float f) {
    union { float f; unsigned u; } v; v.f = f;
    return (unsigned short)((v.u + 0x7FFFu + ((v.u >> 16) & 1u)) >> 16);
}
__device__ inline unsigned bfpack_rne(float lo, float hi) {   // bf16(lo)|bf16(hi)<<16
    return (unsigned)f2bf_rne(lo) | ((unsigned)f2bf_rne(hi) << 16);
}

__global__ __launch_bounds__(512, 2) void fused(
    const float* __restrict__ x,             // N x D fp32
    const int*   __restrict__ idx,           // N
    const float* __restrict__ w,             // NH x D x H fp32
    const float* __restrict__ bias,          // NH x H fp32
    float*       __restrict__ out)           // N x H fp32
{
    __shared__ unsigned short Bl[SH * BPITCH];      // 33.3 KB, [h][d] bf16
    __shared__ unsigned short slist[N_SAMPLES];     // 4 KB
    __shared__ int wcnt[8];

    const int bid  = blockIdx.x;                    // 256 blocks = head x 16 stripes
    const int head = bid >> 4;
    const int h0   = (bid & 15) * SH;
    const int t    = threadIdx.x;
    const int wave = t >> 6;                        // 0..7
    const int lane = t & 63;
    const int l16  = lane & 15;
    const int quad = lane >> 4;

    // ---- idx loads first (oldest in flight; ballot waits only on these) ----
    int myidx[4];
    #pragma unroll
    for (int c = 0; c < 4; ++c)
        myidx[c] = idx[(wave * 4 + c) * 64 + lane];

    // ---- bias early (tiny, reused at epilogue) ----
    const float bv0 = bias[head * HDIM + h0 + l16];
    const float bv1 = bias[head * HDIM + h0 + 16 + l16];

    // ---- issue ALL W loads into regs, NONTEMPORAL (each W line read exactly
    //      once machine-wide: no L3 alloc, no dirty-poison eviction) ----
    const int hh = (t & 7) * 4;                     // 0..28
    const int dg = t >> 3;                          // 0..63, d-range [dg*8, +8)
    const float* wg = w + (size_t)head * DIM * HDIM + h0;
    floatx4 q[8];
    #pragma unroll
    for (int s = 0; s < 8; ++s)
        q[s] = __builtin_nontemporal_load(
                   (const floatx4*)(wg + (size_t)(dg * 8 + s) * HDIM + hh));

    // ---- ballot compaction (overlaps W-load flight; waits only idx) ----
    unsigned long long masks[4];
    {
        int mycnt = 0;
        #pragma unroll
        for (int c = 0; c < 4; ++c) {
            masks[c] = __ballot(myidx[c] == head);
            mycnt += __popcll(masks[c]);
        }
        if (lane == 0) wcnt[wave] = mycnt;
    }
    __syncthreads();                                // wcnt visible
    int cnt = 0, base = 0;
    #pragma unroll
    for (int i = 0; i < 8; ++i) { if (i < wave) base += wcnt[i]; cnt += wcnt[i]; }
    {
        int pos = base;
        #pragma unroll
        for (int c = 0; c < 4; ++c) {
            const unsigned long long m = masks[c];
            if (m & (1ull << lane)) {
                const int rank = __popcll(m & ((1ull << lane) - 1ull));
                slist[pos + rank] = (unsigned short)((wave * 4 + c) * 64 + lane);
            }
            pos += __popcll(m);
        }
    }
    __syncthreads();                                // slist visible (pre-W-drain)

    // ---- ISSUE-EARLY x prefetch: each wave's first m-tile A-rows into regs,
    //      in flight during the W vmcnt-drain + convert + barrier ----
    const int mt = (cnt + 15) >> 4;                 // m-tiles for this head
    floatx4 xr[32];
    if (wave < mt) {
        const int mg  = wave * 16 + l16;
        const int row = slist[mg < cnt ? mg : cnt - 1];
        const float* ap = x + (size_t)row * DIM + quad * 8;
        #pragma unroll
        for (int ks = 0; ks < 16; ++ks) {
            xr[2 * ks]     = *(const floatx4*)(ap + ks * 32);
            xr[2 * ks + 1] = *(const floatx4*)(ap + ks * 32 + 4);
        }
    }

    // ---- convert staged W and write Bl[h][d]: one b128 per h-row; waits
    //      vmcnt on q only (x loads are younger, stay in flight) ----
    #pragma unroll
    for (int k = 0; k < 4; ++k) {
        uint4 o;
        o.x = bfpack_rne(((const float*)&q[0])[k], ((const float*)&q[1])[k]);
        o.y = bfpack_rne(((const float*)&q[2])[k], ((const float*)&q[3])[k]);
        o.z = bfpack_rne(((const float*)&q[4])[k], ((const float*)&q[5])[k]);
        o.w = bfpack_rne(((const float*)&q[6])[k], ((const float*)&q[7])[k]);
        *(uint4*)&Bl[(hh + k) * BPITCH + dg * 8] = o;
    }
    __syncthreads();                                // Bl visible

    // ---- m-loop: wave owns m-tiles j = wave, wave+8, ... (mostly 1/wave) ----
    for (int j = wave; j < mt; j += 8) {
        if (j != wave) {                            // rare second tile: load now
            const int mg  = j * 16 + l16;
            const int row = slist[mg < cnt ? mg : cnt - 1];
            const float* ap = x + (size_t)row * DIM + quad * 8;
            #pragma unroll
            for (int ks = 0; ks < 16; ++ks) {
                xr[2 * ks]     = *(const floatx4*)(ap + ks * 32);
                xr[2 * ks + 1] = *(const floatx4*)(ap + ks * 32 + 4);
            }
        }

        floatx4 acc0 = {0.f, 0.f, 0.f, 0.f};
        floatx4 acc1 = {0.f, 0.f, 0.f, 0.f};
        #pragma unroll
        for (int ks = 0; ks < 16; ++ks) {
            const floatx4 v0 = xr[2 * ks];
            const floatx4 v1 = xr[2 * ks + 1];
            union { bf16x8 v; unsigned u[4]; } A;
            A.u[0] = bfpack_rne(v0.x, v0.y);
            A.u[1] = bfpack_rne(v0.z, v0.w);
            A.u[2] = bfpack_rne(v1.x, v1.y);
            A.u[3] = bfpack_rne(v1.z, v1.w);
            const bf16x8 b0 = *(const bf16x8*)&Bl[l16 * BPITCH + ks * 32 + quad * 8];
            const bf16x8 b1 = *(const bf16x8*)&Bl[(16 + l16) * BPITCH + ks * 32 + quad * 8];
            acc0 = __builtin_amdgcn_mfma_f32_16x16x32_bf16(A.v, b0, acc0, 0, 0, 0);
            acc1 = __builtin_amdgcn_mfma_f32_16x16x32_bf16(A.v, b1, acc1, 0, 0, 0);
        }

        // C[m][n]: n = l16 (h), sample row = quad*4 + r; 64B-contiguous stores,
        // nontemporal (written once, no L3 alloc/dirty churn)
        #pragma unroll
        for (int r = 0; r < 4; ++r) {
            const int mm = j * 16 + quad * 4 + r;
            if (mm < cnt) {
                const int rg = slist[mm];
                __builtin_nontemporal_store(acc0[r] + bv0,
                    out + (size_t)rg * HDIM + h0 + l16);
                __builtin_nontemporal_store(acc1[r] + bv1,
                    out + (size_t)rg * HDIM + h0 + 16 + l16);
            }
        }
    }
}

extern "C" void kernel_launch(void* const* d_in, const int* in_sizes, int n_in,
                              void* d_out, int out_size, void* d_ws, size_t ws_size,
                              hipStream_t stream) {
    const float* x   = (const float*)d_in[0];
    const int*   idx = (const int*)  d_in[1];
    const float* w   = (const float*)d_in[2];
    const float* b   = (const float*)d_in[3];
    float*       out = (float*)d_out;
    (void)d_ws; (void)ws_size;

    fused<<<N_HEADS * (HDIM / SH), 512, 0, stream>>>(x, idx, w, b, out);
}